// Round 15
// baseline (99.005 us; speedup 1.0000x reference)
//
#include <hip/hip_runtime.h>
#include <math.h>

typedef __attribute__((ext_vector_type(8))) short bf16x8;
typedef __attribute__((ext_vector_type(4))) float f32x4;

namespace {
constexpr int Bb  = 4;
constexpr int Tt  = 2048;
constexpr int DM  = 768;
constexpr int Hh  = 4;
constexpr int Dd  = 64;
constexpr int DIM = 256;          // H*D
constexpr int BT  = Bb * Tt;      // 8192
constexpr int CH  = 64;           // chunk length
constexpr int NC  = Tt / CH;      // 32 chunks
constexpr int NQKVG = 1536;       // QKV (768) + gate (768) output cols
constexpr int MT  = BT / 128;     // 64 m-tiles
}

__device__ __forceinline__ float elu1(float x) { return x > 0.f ? x + 1.f : expf(x); }

// fp32 -> bf16, round-to-nearest-even
__device__ __forceinline__ unsigned short f2bf(float f) {
  unsigned int x = __float_as_uint(f);
  unsigned int r = (x + 0x7fffu + ((x >> 16) & 1u)) >> 16;
  return (unsigned short)r;
}
__device__ __forceinline__ float bf2f(unsigned short u) {
  return __uint_as_float((unsigned int)u << 16);
}

__device__ __forceinline__ void gload16(const void* g, void* l) {
  __builtin_amdgcn_global_load_lds(
      (const __attribute__((address_space(1))) void*)g,
      (__attribute__((address_space(3))) void*)l, 16, 0, 0);
}

// ============== GEMM machinery (round-14: 3-ring + frag read-ahead) ==============
struct Stage32 {
  const short* a[2];
  const short* b[2];
  int seg;
  __device__ __forceinline__ void init(const short* Ag, size_t lda,
                                       const short* Bg, size_t ldb, int w, int l) {
    const int c16 = (l & 3) ^ ((l >> 3) & 3);
    seg = w * 2;
#pragma unroll
    for (int j = 0; j < 2; ++j) {
      int row = (seg + j) * 16 + (l >> 2);
      a[j] = Ag + (size_t)row * lda + c16 * 8;
      b[j] = Bg + (size_t)row * ldb + c16 * 8;
    }
  }
  __device__ __forceinline__ void issue(int k0, short* as, short* bs) const {
#pragma unroll
    for (int j = 0; j < 2; ++j) {
      gload16(a[j] + k0, (char*)as + (seg + j) * 1024);
      gload16(b[j] + k0, (char*)bs + (seg + j) * 1024);
    }
  }
};

__device__ __forceinline__ void xcd_tile(int bid, int& mt, int& nt) {
  int xcd = bid & 7;
  int idx = bid >> 3;
  mt = xcd * 8 + (idx & 7);
  nt = idx >> 3;
}

__device__ __forceinline__ void read_frags(const short* as, const short* bs,
                                           bf16x8 (&af)[4], bf16x8 (&bf)[4],
                                           int wr, int wc, int lr, int lg) {
#pragma unroll
  for (int mi = 0; mi < 4; ++mi) {
    int r = wr * 64 + mi * 16 + lr;
    af[mi] = *(const bf16x8*)&as[r * 32 + (lg ^ ((r >> 1) & 3)) * 8];
  }
#pragma unroll
  for (int ni = 0; ni < 4; ++ni) {
    int r = wc * 64 + ni * 16 + lr;
    bf[ni] = *(const bf16x8*)&bs[r * 32 + (lg ^ ((r >> 1) & 3)) * 8];
  }
}

// 3-ring, ONE barrier/step, fragment READ-AHEAD (round-14, proven).
template <int NT>
__device__ __forceinline__ void kloop3p(const Stage32& st,
                                        short* A0, short* A1, short* A2,
                                        short* B0, short* B1, short* B2,
                                        f32x4 (&acc)[4][4], int wr, int wc,
                                        int lr, int lg) {
  st.issue(0, A0, B0);
  st.issue(32, A1, B1);
  asm volatile("s_waitcnt vmcnt(4)" ::: "memory");
  __builtin_amdgcn_s_barrier();
  bf16x8 af[4], bf[4];
  read_frags(A0, B0, af, bf, wr, wc, lr, lg);
  asm volatile("s_waitcnt lgkmcnt(0)" ::: "memory");
  __builtin_amdgcn_sched_barrier(0);
#pragma unroll
  for (int t = 0; t < NT; ++t) {
    if (t + 2 < NT) {
      short* an = (((t + 2) % 3) == 0) ? A0 : (((t + 2) % 3) == 1) ? A1 : A2;
      short* bn = (((t + 2) % 3) == 0) ? B0 : (((t + 2) % 3) == 1) ? B1 : B2;
      st.issue((t + 2) * 32, an, bn);
    }
    __builtin_amdgcn_s_setprio(1);
#pragma unroll
    for (int mi = 0; mi < 4; ++mi)
#pragma unroll
      for (int ni = 0; ni < 4; ++ni)
        acc[mi][ni] = __builtin_amdgcn_mfma_f32_16x16x32_bf16(
            af[mi], bf[ni], acc[mi][ni], 0, 0, 0);
    __builtin_amdgcn_s_setprio(0);
    if (t + 1 < NT) {
      if (t + 2 < NT)
        asm volatile("s_waitcnt vmcnt(4)" ::: "memory");
      else
        asm volatile("s_waitcnt vmcnt(0)" ::: "memory");
      __builtin_amdgcn_s_barrier();
      short* as = (((t + 1) % 3) == 0) ? A0 : (((t + 1) % 3) == 1) ? A1 : A2;
      short* bs = (((t + 1) % 3) == 0) ? B0 : (((t + 1) % 3) == 1) ? B1 : B2;
      read_frags(as, bs, af, bf, wr, wc, lr, lg);
      asm volatile("s_waitcnt lgkmcnt(0)" ::: "memory");
      __builtin_amdgcn_sched_barrier(0);
    }
  }
}

// ---------------------------------------------------------------------------
// k_prep: fused input cast + weight transposes (unchanged).
// ---------------------------------------------------------------------------
__global__ __launch_bounds__(256) void k_prep(
    const float* __restrict__ x, const float* __restrict__ Wq,
    const float* __restrict__ Wk, const float* __restrict__ Wv,
    const float* __restrict__ Wg, const float* __restrict__ Wo,
    unsigned short* __restrict__ xb, unsigned short* __restrict__ WT,
    unsigned short* __restrict__ WoT) {
  int bid = blockIdx.x;
  if (bid < 3072) {
    int i = bid * 256 + threadIdx.x;
    const float4* p = (const float4*)(x + (size_t)i * 8);
    float4 a = p[0], b = p[1];
    union { unsigned short u[8]; uint4 v; } r;
    r.u[0] = f2bf(a.x); r.u[1] = f2bf(a.y); r.u[2] = f2bf(a.z); r.u[3] = f2bf(a.w);
    r.u[4] = f2bf(b.x); r.u[5] = f2bf(b.y); r.u[6] = f2bf(b.z); r.u[7] = f2bf(b.w);
    *(uint4*)(xb + (size_t)i * 8) = r.v;
    return;
  }
  __shared__ float t[32][33];
  int idx = bid - 3072;
  const float* src;
  unsigned short* out;
  int K, N, n_off, ldo;
  if (idx < 576) {
    int z = idx / 192;
    idx %= 192;
    src = (z == 0) ? Wq : (z == 1) ? Wk : Wv;
    out = WT; K = 768; N = 256; n_off = z * 256; ldo = 768;
  } else if (idx < 1152) {
    idx -= 576;
    src = Wg; out = WT; K = 768; N = 768; n_off = 768; ldo = 768;
  } else {
    idx -= 1152;
    src = Wo; out = WoT; K = 256; N = 768; n_off = 0; ldo = 256;
  }
  int kt = idx % (K / 32), nt = idx / (K / 32);
  int k0 = kt * 32, n0 = nt * 32;
  const int tx = threadIdx.x & 31, ty = threadIdx.x >> 5;
  for (int i = ty; i < 32; i += 8)
    t[i][tx] = src[(size_t)(k0 + i) * N + n0 + tx];
  __syncthreads();
  for (int i = ty; i < 32; i += 8)
    out[(size_t)(n_off + n0 + i) * ldo + k0 + tx] = f2bf(t[tx][i]);
}

// ---------------------------------------------------------------------------
// GEMM1 (unchanged, round 14).
// ---------------------------------------------------------------------------
__global__ __launch_bounds__(256, 3) void k_gemm1(
    const unsigned short* __restrict__ xb, const unsigned short* __restrict__ WT,
    unsigned short* __restrict__ Q, unsigned short* __restrict__ K,
    unsigned short* __restrict__ V, unsigned short* __restrict__ G) {
  __shared__ __align__(16) char smem[49152];
  short* A0 = (short*)smem;
  short* A1 = (short*)(smem + 8192);
  short* A2 = (short*)(smem + 16384);
  short* B0 = (short*)(smem + 24576);
  short* B1 = (short*)(smem + 32768);
  short* B2 = (short*)(smem + 40960);
  const int tid = threadIdx.x;
  const int w = tid >> 6, l = tid & 63;
  const int lr = l & 15, lg = l >> 4;
  const int wr = w >> 1, wc = w & 1;
  int mt, nt;
  xcd_tile(blockIdx.x, mt, nt);
  const int m0 = mt * 128, n0 = nt * 128;

  Stage32 st;
  st.init((const short*)xb + (size_t)m0 * DM, DM,
          (const short*)WT + (size_t)n0 * DM, DM, w, l);

  f32x4 acc[4][4];
#pragma unroll
  for (int i = 0; i < 4; ++i)
#pragma unroll
    for (int j = 0; j < 4; ++j) acc[i][j] = (f32x4){0.f, 0.f, 0.f, 0.f};

  kloop3p<DM / 32>(st, A0, A1, A2, B0, B1, B2, acc, wr, wc, lr, lg);
  __syncthreads();

  const int ttype = (n0 < 512) ? 0 : (n0 < 768) ? 1 : 2;  // eluQK / V / G
  unsigned short* Cs = (unsigned short*)smem;              // 128x128 bf16
#pragma unroll
  for (int mi = 0; mi < 4; ++mi)
#pragma unroll
    for (int ni = 0; ni < 4; ++ni)
#pragma unroll
      for (int r = 0; r < 4; ++r) {
        float v = acc[mi][ni][r];
        if (ttype == 0) v = elu1(v);
        else if (ttype == 2) v = 1.f / (1.f + expf(-v));
        Cs[(wr * 64 + mi * 16 + lg * 4 + r) * 128 + wc * 64 + ni * 16 + lr] =
            f2bf(v);
      }
  __syncthreads();
  unsigned short* dst;
  int ldd, cb;
  if (n0 < 256)      { dst = Q; ldd = DIM; cb = n0; }
  else if (n0 < 512) { dst = K; ldd = DIM; cb = n0 - 256; }
  else if (n0 < 768) { dst = V; ldd = DIM; cb = n0 - 512; }
  else               { dst = G; ldd = DM;  cb = n0 - 768; }
  const uint4* Cv = (const uint4*)Cs;
#pragma unroll
  for (int i = 0; i < 8; ++i) {
    int idx = tid + i * 256;            // 2048 uint4 = 128x128 bf16
    int urow = idx >> 4, uc = idx & 15;
    *(uint4*)(dst + (size_t)(m0 + urow) * ldd + cb + uc * 8) = Cv[idx];
  }
}

// ---------------------------------------------------------------------------
// K2 (MFMA): S_c = K^T V per chunk (bf16 out, per-chunk, NOT prefixed);
// z_c = colsum(K) (fp32, per-chunk). (round-13)
// ---------------------------------------------------------------------------
__global__ __launch_bounds__(256) void k_chunksum(
    const unsigned short* __restrict__ K, const unsigned short* __restrict__ V,
    unsigned short* __restrict__ Sc, float* __restrict__ zc) {
  __shared__ __align__(16) char smem[16384];
  short* Kt = (short*)smem;            // [64 d][64 t] swz
  short* Vt = (short*)(smem + 8192);   // [64 e][64 t] swz
  const int c = blockIdx.x, h = blockIdx.y, b = blockIdx.z;
  const int tid = threadIdx.x;
  const int w = tid >> 6, l = tid & 63;
  const int lr = l & 15, lg = l >> 4;
  const size_t rowbase = ((size_t)(b * Tt + c * CH)) * DIM + h * Dd;

#pragma unroll
  for (int it = 0; it < 4; ++it) {
    int idx = tid + it * 256;
    int t = idx >> 4, d4 = idx & 15;
    short4 k4 = *(const short4*)((const short*)K + rowbase + (size_t)t * DIM + d4 * 4);
    short4 v4 = *(const short4*)((const short*)V + rowbase + (size_t)t * DIM + d4 * 4);
    const short* kk = (const short*)&k4;
    const short* vv = (const short*)&v4;
#pragma unroll
    for (int j = 0; j < 4; ++j) {
      int e = d4 * 4 + j;
      int sl = ((t >> 3) ^ (e & 7)) * 16 + (t & 7) * 2;
      *(short*)((char*)Kt + e * 128 + sl) = kk[j];
      *(short*)((char*)Vt + e * 128 + sl) = vv[j];
    }
  }
  __syncthreads();

  if (tid < Dd) {
    float s = 0.f;
    for (int t = 0; t < CH; ++t) {
      unsigned short u = *(const unsigned short*)(
          (char*)Kt + tid * 128 + (((t >> 3) ^ (tid & 7)) * 16) + (t & 7) * 2);
      s += bf2f(u);
    }
    zc[((size_t)(b * Hh + h) * NC + c) * Dd + tid] = s;
  }

  f32x4 a[4];
#pragma unroll
  for (int nf = 0; nf < 4; ++nf) a[nf] = (f32x4){0.f, 0.f, 0.f, 0.f};
  const int rd = w * 16 + lr;
#pragma unroll
  for (int ks = 0; ks < 2; ++ks) {
    bf16x8 af = *(const bf16x8*)((char*)Kt + rd * 128 +
                                 (((ks * 4 + lg) ^ (rd & 7)) * 16));
#pragma unroll
    for (int nf = 0; nf < 4; ++nf) {
      int re = nf * 16 + lr;
      bf16x8 bf = *(const bf16x8*)((char*)Vt + re * 128 +
                                   (((ks * 4 + lg) ^ (re & 7)) * 16));
      a[nf] = __builtin_amdgcn_mfma_f32_16x16x32_bf16(af, bf, a[nf], 0, 0, 0);
    }
  }
  __syncthreads();

  unsigned short* Cb = (unsigned short*)smem;  // [64][64] bf16
#pragma unroll
  for (int nf = 0; nf < 4; ++nf)
#pragma unroll
    for (int r = 0; r < 4; ++r)
      Cb[(w * 16 + lg * 4 + r) * 64 + nf * 16 + lr] = f2bf(a[nf][r]);
  __syncthreads();
  const size_t base = ((size_t)(b * Hh + h) * NC + c) * (Dd * Dd);
  const uint4* Cv = (const uint4*)Cb;
#pragma unroll
  for (int it = 0; it < 2; ++it) {
    int idx = tid + it * 256;   // 512 uint4 = 4096 bf16
    *(uint4*)&Sc[base + (size_t)idx * 8] = Cv[idx];
  }
}

// ---------------------------------------------------------------------------
// K4 (MFMA): per-chunk output. Prefix of S_c / z_c computed ON THE FLY
// (k_scan deleted): St = sum_{c'<c} S_{c'} (fp32 accum over bf16 chunks,
// L2-resident), zs = sum_{c'<c} z_{c'}.
// ---------------------------------------------------------------------------
__global__ __launch_bounds__(256) void k_out(
    const unsigned short* __restrict__ Q, const unsigned short* __restrict__ K,
    const unsigned short* __restrict__ V, const unsigned short* __restrict__ Sc,
    const float* __restrict__ zc, unsigned short* __restrict__ O) {
  __shared__ __align__(16) char smem[41216];
  short* Qs = (short*)smem;            // [64 t][64 d] swz
  short* Ks = (short*)(smem + 8192);   // [64 s][64 d] swz
  short* Vt = (short*)(smem + 16384);  // [64 e][64 s] swz
  short* St = (short*)(smem + 24576);  // [64 e][64 d] swz
  short* Ps = (short*)(smem + 32768);  // [64 t][64 s] swz; later out staging
  float* zs = (float*)(smem + 40960);
  const int c = blockIdx.x, h = blockIdx.y, b = blockIdx.z;
  const int tid = threadIdx.x;
  const int w = tid >> 6, l = tid & 63;
  const int lr = l & 15, lg = l >> 4;
  const size_t rowbase = ((size_t)(b * Tt + c * CH)) * DIM + h * Dd;

  {
    const int c16 = (l & 7) ^ ((l >> 3) & 7);
#pragma unroll
    for (int i = 0; i < 2; ++i) {
      int row = i * 32 + w * 8 + (l >> 3);
      gload16((const short*)Q + rowbase + (size_t)row * DIM + c16 * 8,
              (char*)Qs + (i * 32 + w * 8) * 128);
      gload16((const short*)K + rowbase + (size_t)row * DIM + c16 * 8,
              (char*)Ks + (i * 32 + w * 8) * 128);
    }
  }
  const size_t bh = (size_t)(b * Hh + h);
  // z prefix on the fly
  if (tid < Dd) {
    float rz = 0.f;
    for (int cp = 0; cp < c; ++cp)
      rz += zc[(bh * NC + cp) * Dd + tid];
    zs[tid] = rz;
  }
  // V staging + S prefix on the fly
#pragma unroll
  for (int it = 0; it < 4; ++it) {
    int idx = tid + it * 256;
    int t = idx >> 4, d4 = idx & 15;
    short4 v4 = *(const short4*)((const short*)V + rowbase + (size_t)t * DIM + d4 * 4);
    const short* vv = (const short*)&v4;
#pragma unroll
    for (int j = 0; j < 4; ++j) {
      int e = d4 * 4 + j;
      *(short*)((char*)Vt + e * 128 + (((t >> 3) ^ (e & 7)) * 16) + (t & 7) * 2) = vv[j];
    }
    float a0 = 0.f, a1 = 0.f, a2 = 0.f, a3 = 0.f;
    const unsigned short* sp = Sc + bh * NC * (Dd * Dd) + (size_t)t * 64 + d4 * 4;
    for (int cp = 0; cp < c; ++cp) {
      short4 s4 = *(const short4*)(sp + (size_t)cp * (Dd * Dd));
      a0 += bf2f((unsigned short)s4.x);
      a1 += bf2f((unsigned short)s4.y);
      a2 += bf2f((unsigned short)s4.z);
      a3 += bf2f((unsigned short)s4.w);
    }
    float av[4] = {a0, a1, a2, a3};
#pragma unroll
    for (int j = 0; j < 4; ++j) {
      int e = d4 * 4 + j;  // t here is the d index of S
      *(short*)((char*)St + e * 128 + (((t >> 3) ^ (e & 7)) * 16) + (t & 7) * 2) =
          (short)f2bf(av[j]);
    }
  }
  __syncthreads();

  f32x4 a0q[4];
#pragma unroll
  for (int nf = 0; nf < 4; ++nf) a0q[nf] = (f32x4){0.f, 0.f, 0.f, 0.f};
  const int rq = w * 16 + lr;
#pragma unroll
  for (int ks = 0; ks < 2; ++ks) {
    bf16x8 af = *(const bf16x8*)((char*)Qs + rq * 128 +
                                 (((ks * 4 + lg) ^ (rq & 7)) * 16));
#pragma unroll
    for (int nf = 0; nf < 4; ++nf) {
      int rk = nf * 16 + lr;
      bf16x8 bf = *(const bf16x8*)((char*)Ks + rk * 128 +
                                   (((ks * 4 + lg) ^ (rk & 7)) * 16));
      a0q[nf] = __builtin_amdgcn_mfma_f32_16x16x32_bf16(af, bf, a0q[nf], 0, 0, 0);
    }
  }

  float part[4] = {0.f, 0.f, 0.f, 0.f};
#pragma unroll
  for (int nf = 0; nf < 4; ++nf) {
    int col = nf * 16 + lr;
#pragma unroll
    for (int r = 0; r < 4; ++r) {
      int row = w * 16 + lg * 4 + r;
      float av = (col <= row) ? a0q[nf][r] : 0.f;
      part[r] += av;
      *(short*)((char*)Ps + row * 128 +
                ((((nf * 2) + (lr >> 3)) ^ (row & 7)) * 16) + (lr & 7) * 2) =
          (short)f2bf(av);
    }
  }
#pragma unroll
  for (int r = 0; r < 4; ++r) {
    int row = w * 16 + lg * 4 + r;
#pragma unroll
    for (int j = 0; j < 4; ++j) {
      int d = lr + j * 16;
      unsigned short qu = *(const unsigned short*)(
          (char*)Qs + row * 128 + (((d >> 3) ^ (row & 7)) * 16) + (d & 7) * 2);
      part[r] += bf2f(qu) * zs[d];
    }
  }
  float inv[4];
#pragma unroll
  for (int r = 0; r < 4; ++r) {
    float s = part[r];
    s += __shfl_xor(s, 1);
    s += __shfl_xor(s, 2);
    s += __shfl_xor(s, 4);
    s += __shfl_xor(s, 8);
    inv[r] = 1.f / fmaxf(s, 1e-6f);
  }
  __syncthreads();

  f32x4 a1q[4];
#pragma unroll
  for (int nf = 0; nf < 4; ++nf) a1q[nf] = (f32x4){0.f, 0.f, 0.f, 0.f};
#pragma unroll
  for (int ks = 0; ks < 4; ++ks) {
    const char* abase = (ks < 2) ? (const char*)Ps : (const char*)Qs;
    const char* bbase = (ks < 2) ? (const char*)Vt : (const char*)St;
    int kslot = (ks & 1) * 4 + lg;
    bf16x8 af = *(const bf16x8*)(abase + rq * 128 + ((kslot ^ (rq & 7)) * 16));
#pragma unroll
    for (int nf = 0; nf < 4; ++nf) {
      int re = nf * 16 + lr;
      bf16x8 bf = *(const bf16x8*)(bbase + re * 128 + ((kslot ^ (re & 7)) * 16));
      a1q[nf] = __builtin_amdgcn_mfma_f32_16x16x32_bf16(af, bf, a1q[nf], 0, 0, 0);
    }
  }
  __syncthreads();

#pragma unroll
  for (int nf = 0; nf < 4; ++nf)
#pragma unroll
    for (int r = 0; r < 4; ++r) {
      int row = w * 16 + lg * 4 + r;
      Ps[row * 64 + nf * 16 + lr] = (short)f2bf(a1q[nf][r] * inv[r]);
    }
  __syncthreads();
  const uint4* Pv = (const uint4*)Ps;
#pragma unroll
  for (int i = 0; i < 2; ++i) {
    int idx = tid + i * 256;
    int row = idx >> 3, uc = idx & 7;
    *(uint4*)((unsigned short*)O + rowbase + (size_t)row * DIM + uc * 8) = Pv[idx];
  }
}

// ---------------------------------------------------------------------------
// GEMM2 (unchanged, round 14).
// ---------------------------------------------------------------------------
__global__ __launch_bounds__(256, 3) void k_gemm2(
    const unsigned short* __restrict__ Ob, const unsigned short* __restrict__ WoT,
    const unsigned short* __restrict__ G, float* __restrict__ out) {
  __shared__ __align__(16) char smem[49152];
  short* A0 = (short*)smem;
  short* A1 = (short*)(smem + 8192);
  short* A2 = (short*)(smem + 16384);
  short* B0 = (short*)(smem + 24576);
  short* B1 = (short*)(smem + 32768);
  short* B2 = (short*)(smem + 40960);
  const int tid = threadIdx.x;
  const int w = tid >> 6, l = tid & 63;
  const int lr = l & 15, lg = l >> 4;
  const int wr = w >> 1, wc = w & 1;
  int mt, nt;
  xcd_tile(blockIdx.x, mt, nt);
  const int m0 = mt * 128, n0 = nt * 128;

  Stage32 st;
  st.init((const short*)Ob + (size_t)m0 * DIM, DIM,
          (const short*)WoT + (size_t)n0 * DIM, DIM, w, l);

  f32x4 acc[4][4];
#pragma unroll
  for (int i = 0; i < 4; ++i)
#pragma unroll
    for (int j = 0; j < 4; ++j) acc[i][j] = (f32x4){0.f, 0.f, 0.f, 0.f};

  kloop3p<DIM / 32>(st, A0, A1, A2, B0, B1, B2, acc, wr, wc, lr, lg);

  float* Cf = (float*)smem;
#pragma unroll
  for (int half = 0; half < 2; ++half) {
    __syncthreads();
    if (wr == half) {
#pragma unroll
      for (int mi = 0; mi < 4; ++mi)
#pragma unroll
        for (int ni = 0; ni < 4; ++ni)
#pragma unroll
          for (int r = 0; r < 4; ++r)
            Cf[(mi * 16 + lg * 4 + r) * 128 + wc * 64 + ni * 16 + lr] =
                acc[mi][ni][r];
    }
    __syncthreads();
    const float4* Cv = (const float4*)Cf;
#pragma unroll
    for (int i = 0; i < 8; ++i) {
      int idx = tid + i * 256;          // 2048 float4 = 64x128 fp32
      int urow = idx >> 5, uc = idx & 31;
      float4 cv = Cv[idx];
      size_t go = (size_t)(m0 + half * 64 + urow) * DM + n0 + uc * 4;
      short4 g4 = *(const short4*)(G + go);
      float4 ov;
      ov.x = cv.x * bf2f(g4.x);
      ov.y = cv.y * bf2f(g4.y);
      ov.z = cv.z * bf2f(g4.z);
      ov.w = cv.w * bf2f(g4.w);
      *(float4*)(out + go) = ov;
    }
  }
}

// ---------------------------------------------------------------------------
extern "C" void kernel_launch(void* const* d_in, const int* in_sizes, int n_in,
                              void* d_out, int out_size, void* d_ws,
                              size_t ws_size, hipStream_t stream) {
  const float* x  = (const float*)d_in[0];
  const float* Wq = (const float*)d_in[1];
  const float* Wk = (const float*)d_in[2];
  const float* Wv = (const float*)d_in[3];
  const float* Wo = (const float*)d_in[4];
  const float* Wg = (const float*)d_in[5];
  float* out = (float*)d_out;

  char* p = (char*)d_ws;
  size_t off = 0;
  auto alloc = [&](size_t bytes) {
    void* r = p + off;
    off = (off + bytes + 255) & ~(size_t)255;
    return r;
  };
  unsigned short* xb  = (unsigned short*)alloc((size_t)BT * DM * 2);
  unsigned short* WT  = (unsigned short*)alloc((size_t)NQKVG * DM * 2);
  unsigned short* WoT = (unsigned short*)alloc((size_t)DM * DIM * 2);
  unsigned short* Q   = (unsigned short*)alloc((size_t)BT * DIM * 2);
  unsigned short* Kf  = (unsigned short*)alloc((size_t)BT * DIM * 2);
  unsigned short* Vf  = (unsigned short*)alloc((size_t)BT * DIM * 2);
  unsigned short* G   = (unsigned short*)alloc((size_t)BT * DM * 2);
  unsigned short* Ob  = (unsigned short*)alloc((size_t)BT * DIM * 2);
  unsigned short* Sc  = (unsigned short*)alloc((size_t)Bb * Hh * NC * Dd * Dd * 2);
  float* zc = (float*)alloc((size_t)Bb * Hh * NC * Dd * 4);

  // 1. fused input cast + weight transposes
  k_prep<<<dim3(3072 + 1344), dim3(256), 0, stream>>>(x, Wq, Wk, Wv, Wg, Wo,
                                                      xb, WT, WoT);

  // 2. fused QKV + gate projection (MFMA), N=1536
  k_gemm1<<<dim3(MT * (NQKVG / 128)), dim3(256), 0, stream>>>(
      xb, WT, Q, Kf, Vf, G);

  // 3. chunked linear attention (per-chunk sums, prefix fused into k_out)
  k_chunksum<<<dim3(NC, Hh, Bb), dim3(256), 0, stream>>>(Kf, Vf, Sc, zc);
  k_out<<<dim3(NC, Hh, Bb), dim3(256), 0, stream>>>(Q, Kf, Vf, Sc, zc, Ob);

  // 4. output GEMM * gate (MFMA)
  k_gemm2<<<dim3(MT * (DM / 128)), dim3(256), 0, stream>>>(Ob, WoT, G, out);
}

// Round 16
// 73.818 us; speedup vs baseline: 1.3412x; 1.3412x over previous
//
#include <hip/hip_runtime.h>
#include <math.h>

typedef __attribute__((ext_vector_type(8))) short bf16x8;
typedef __attribute__((ext_vector_type(4))) float f32x4;

namespace {
constexpr int Bb  = 4;
constexpr int Tt  = 2048;
constexpr int DM  = 768;
constexpr int Hh  = 4;
constexpr int Dd  = 64;
constexpr int DIM = 256;          // H*D
constexpr int BT  = Bb * Tt;      // 8192
constexpr int CH  = 64;           // chunk length
constexpr int NC  = Tt / CH;      // 32 chunks
constexpr int NQKVG = 1536;       // QKV (768) + gate (768) output cols
constexpr int MT  = BT / 128;     // 64 m-tiles
}

__device__ __forceinline__ float elu1(float x) { return x > 0.f ? x + 1.f : expf(x); }

// fp32 -> bf16, round-to-nearest-even
__device__ __forceinline__ unsigned short f2bf(float f) {
  unsigned int x = __float_as_uint(f);
  unsigned int r = (x + 0x7fffu + ((x >> 16) & 1u)) >> 16;
  return (unsigned short)r;
}
__device__ __forceinline__ float bf2f(unsigned short u) {
  return __uint_as_float((unsigned int)u << 16);
}

__device__ __forceinline__ void gload16(const void* g, void* l) {
  __builtin_amdgcn_global_load_lds(
      (const __attribute__((address_space(1))) void*)g,
      (__attribute__((address_space(3))) void*)l, 16, 0, 0);
}

// ============== GEMM machinery (round-14: 3-ring + frag read-ahead) ==============
// BK=32 staging (tile = 128 rows x 32 bf16 = 8KB, 8 segs of 1KB).
// XOR source-swizzle (T2, rule #21): LDS dest linear; fetched 16B-column
// c16' = (l&3)^((l>>3)&3); readers XOR their 16B slot with ((row>>1)&3).
struct Stage32 {
  const short* a[2];
  const short* b[2];
  int seg;
  __device__ __forceinline__ void init(const short* Ag, size_t lda,
                                       const short* Bg, size_t ldb, int w, int l) {
    const int c16 = (l & 3) ^ ((l >> 3) & 3);
    seg = w * 2;
#pragma unroll
    for (int j = 0; j < 2; ++j) {
      int row = (seg + j) * 16 + (l >> 2);
      a[j] = Ag + (size_t)row * lda + c16 * 8;
      b[j] = Bg + (size_t)row * ldb + c16 * 8;
    }
  }
  __device__ __forceinline__ void issue(int k0, short* as, short* bs) const {
#pragma unroll
    for (int j = 0; j < 2; ++j) {
      gload16(a[j] + k0, (char*)as + (seg + j) * 1024);
      gload16(b[j] + k0, (char*)bs + (seg + j) * 1024);
    }
  }
};

__device__ __forceinline__ void xcd_tile(int bid, int& mt, int& nt) {
  int xcd = bid & 7;
  int idx = bid >> 3;
  mt = xcd * 8 + (idx & 7);
  nt = idx >> 3;
}

__device__ __forceinline__ void read_frags(const short* as, const short* bs,
                                           bf16x8 (&af)[4], bf16x8 (&bf)[4],
                                           int wr, int wc, int lr, int lg) {
#pragma unroll
  for (int mi = 0; mi < 4; ++mi) {
    int r = wr * 64 + mi * 16 + lr;
    af[mi] = *(const bf16x8*)&as[r * 32 + (lg ^ ((r >> 1) & 3)) * 8];
  }
#pragma unroll
  for (int ni = 0; ni < 4; ++ni) {
    int r = wc * 64 + ni * 16 + lr;
    bf[ni] = *(const bf16x8*)&bs[r * 32 + (lg ^ ((r >> 1) & 3)) * 8];
  }
}

// 3-ring, ONE barrier/step, fragment READ-AHEAD (round-14, proven).
template <int NT>
__device__ __forceinline__ void kloop3p(const Stage32& st,
                                        short* A0, short* A1, short* A2,
                                        short* B0, short* B1, short* B2,
                                        f32x4 (&acc)[4][4], int wr, int wc,
                                        int lr, int lg) {
  st.issue(0, A0, B0);
  st.issue(32, A1, B1);
  asm volatile("s_waitcnt vmcnt(4)" ::: "memory");
  __builtin_amdgcn_s_barrier();
  bf16x8 af[4], bf[4];
  read_frags(A0, B0, af, bf, wr, wc, lr, lg);
  asm volatile("s_waitcnt lgkmcnt(0)" ::: "memory");
  __builtin_amdgcn_sched_barrier(0);
#pragma unroll
  for (int t = 0; t < NT; ++t) {
    if (t + 2 < NT) {
      short* an = (((t + 2) % 3) == 0) ? A0 : (((t + 2) % 3) == 1) ? A1 : A2;
      short* bn = (((t + 2) % 3) == 0) ? B0 : (((t + 2) % 3) == 1) ? B1 : B2;
      st.issue((t + 2) * 32, an, bn);
    }
    __builtin_amdgcn_s_setprio(1);
#pragma unroll
    for (int mi = 0; mi < 4; ++mi)
#pragma unroll
      for (int ni = 0; ni < 4; ++ni)
        acc[mi][ni] = __builtin_amdgcn_mfma_f32_16x16x32_bf16(
            af[mi], bf[ni], acc[mi][ni], 0, 0, 0);
    __builtin_amdgcn_s_setprio(0);
    if (t + 1 < NT) {
      if (t + 2 < NT)
        asm volatile("s_waitcnt vmcnt(4)" ::: "memory");
      else
        asm volatile("s_waitcnt vmcnt(0)" ::: "memory");
      __builtin_amdgcn_s_barrier();
      short* as = (((t + 1) % 3) == 0) ? A0 : (((t + 1) % 3) == 1) ? A1 : A2;
      short* bs = (((t + 1) % 3) == 0) ? B0 : (((t + 1) % 3) == 1) ? B1 : B2;
      read_frags(as, bs, af, bf, wr, wc, lr, lg);
      asm volatile("s_waitcnt lgkmcnt(0)" ::: "memory");
      __builtin_amdgcn_sched_barrier(0);
    }
  }
}

// ---------------------------------------------------------------------------
// k_prep: fused input cast + weight transposes.
// ---------------------------------------------------------------------------
__global__ __launch_bounds__(256) void k_prep(
    const float* __restrict__ x, const float* __restrict__ Wq,
    const float* __restrict__ Wk, const float* __restrict__ Wv,
    const float* __restrict__ Wg, const float* __restrict__ Wo,
    unsigned short* __restrict__ xb, unsigned short* __restrict__ WT,
    unsigned short* __restrict__ WoT) {
  int bid = blockIdx.x;
  if (bid < 3072) {
    int i = bid * 256 + threadIdx.x;
    const float4* p = (const float4*)(x + (size_t)i * 8);
    float4 a = p[0], b = p[1];
    union { unsigned short u[8]; uint4 v; } r;
    r.u[0] = f2bf(a.x); r.u[1] = f2bf(a.y); r.u[2] = f2bf(a.z); r.u[3] = f2bf(a.w);
    r.u[4] = f2bf(b.x); r.u[5] = f2bf(b.y); r.u[6] = f2bf(b.z); r.u[7] = f2bf(b.w);
    *(uint4*)(xb + (size_t)i * 8) = r.v;
    return;
  }
  __shared__ float t[32][33];
  int idx = bid - 3072;
  const float* src;
  unsigned short* out;
  int K, N, n_off, ldo;
  if (idx < 576) {
    int z = idx / 192;
    idx %= 192;
    src = (z == 0) ? Wq : (z == 1) ? Wk : Wv;
    out = WT; K = 768; N = 256; n_off = z * 256; ldo = 768;
  } else if (idx < 1152) {
    idx -= 576;
    src = Wg; out = WT; K = 768; N = 768; n_off = 768; ldo = 768;
  } else {
    idx -= 1152;
    src = Wo; out = WoT; K = 256; N = 768; n_off = 0; ldo = 256;
  }
  int kt = idx % (K / 32), nt = idx / (K / 32);
  int k0 = kt * 32, n0 = nt * 32;
  const int tx = threadIdx.x & 31, ty = threadIdx.x >> 5;
  for (int i = ty; i < 32; i += 8)
    t[i][tx] = src[(size_t)(k0 + i) * N + n0 + tx];
  __syncthreads();
  for (int i = ty; i < 32; i += 8)
    out[(size_t)(n_off + n0 + i) * ldo + k0 + tx] = f2bf(t[tx][i]);
}

// ---------------------------------------------------------------------------
// GEMM1: [QKVG] = x @ [Wq|Wk|Wv|Wg]^T.  M=8192, K=768, N=1536.
// 128x128 tile, 4 waves, BK=32, 3-ring LDS (48KB) -> 3 blocks/CU,
// frag read-ahead pipeline.
// ---------------------------------------------------------------------------
__global__ __launch_bounds__(256, 3) void k_gemm1(
    const unsigned short* __restrict__ xb, const unsigned short* __restrict__ WT,
    unsigned short* __restrict__ Q, unsigned short* __restrict__ K,
    unsigned short* __restrict__ V, unsigned short* __restrict__ G) {
  __shared__ __align__(16) char smem[49152];
  short* A0 = (short*)smem;
  short* A1 = (short*)(smem + 8192);
  short* A2 = (short*)(smem + 16384);
  short* B0 = (short*)(smem + 24576);
  short* B1 = (short*)(smem + 32768);
  short* B2 = (short*)(smem + 40960);
  const int tid = threadIdx.x;
  const int w = tid >> 6, l = tid & 63;
  const int lr = l & 15, lg = l >> 4;
  const int wr = w >> 1, wc = w & 1;
  int mt, nt;
  xcd_tile(blockIdx.x, mt, nt);
  const int m0 = mt * 128, n0 = nt * 128;

  Stage32 st;
  st.init((const short*)xb + (size_t)m0 * DM, DM,
          (const short*)WT + (size_t)n0 * DM, DM, w, l);

  f32x4 acc[4][4];
#pragma unroll
  for (int i = 0; i < 4; ++i)
#pragma unroll
    for (int j = 0; j < 4; ++j) acc[i][j] = (f32x4){0.f, 0.f, 0.f, 0.f};

  kloop3p<DM / 32>(st, A0, A1, A2, B0, B1, B2, acc, wr, wc, lr, lg);
  __syncthreads();

  // ---- epilogue: activation + repack through LDS (32KB), 16B stores ----
  const int ttype = (n0 < 512) ? 0 : (n0 < 768) ? 1 : 2;  // eluQK / V / G
  unsigned short* Cs = (unsigned short*)smem;              // 128x128 bf16
#pragma unroll
  for (int mi = 0; mi < 4; ++mi)
#pragma unroll
    for (int ni = 0; ni < 4; ++ni)
#pragma unroll
      for (int r = 0; r < 4; ++r) {
        float v = acc[mi][ni][r];
        if (ttype == 0) v = elu1(v);
        else if (ttype == 2) v = 1.f / (1.f + expf(-v));
        Cs[(wr * 64 + mi * 16 + lg * 4 + r) * 128 + wc * 64 + ni * 16 + lr] =
            f2bf(v);
      }
  __syncthreads();
  unsigned short* dst;
  int ldd, cb;
  if (n0 < 256)      { dst = Q; ldd = DIM; cb = n0; }
  else if (n0 < 512) { dst = K; ldd = DIM; cb = n0 - 256; }
  else if (n0 < 768) { dst = V; ldd = DIM; cb = n0 - 512; }
  else               { dst = G; ldd = DM;  cb = n0 - 768; }
  const uint4* Cv = (const uint4*)Cs;
#pragma unroll
  for (int i = 0; i < 8; ++i) {
    int idx = tid + i * 256;            // 2048 uint4 = 128x128 bf16
    int urow = idx >> 4, uc = idx & 15;
    *(uint4*)(dst + (size_t)(m0 + urow) * ldd + cb + uc * 8) = Cv[idx];
  }
}

// ---------------------------------------------------------------------------
// K2 (MFMA): S_c = K^T V per chunk (bf16 out); z_c = colsum(K) (fp32).
// ---------------------------------------------------------------------------
__global__ __launch_bounds__(256) void k_chunksum(
    const unsigned short* __restrict__ K, const unsigned short* __restrict__ V,
    unsigned short* __restrict__ Sc, float* __restrict__ zc) {
  __shared__ __align__(16) char smem[16384];
  short* Kt = (short*)smem;            // [64 d][64 t] swz
  short* Vt = (short*)(smem + 8192);   // [64 e][64 t] swz
  const int c = blockIdx.x, h = blockIdx.y, b = blockIdx.z;
  const int tid = threadIdx.x;
  const int w = tid >> 6, l = tid & 63;
  const int lr = l & 15, lg = l >> 4;
  const size_t rowbase = ((size_t)(b * Tt + c * CH)) * DIM + h * Dd;

#pragma unroll
  for (int it = 0; it < 4; ++it) {
    int idx = tid + it * 256;
    int t = idx >> 4, d4 = idx & 15;
    short4 k4 = *(const short4*)((const short*)K + rowbase + (size_t)t * DIM + d4 * 4);
    short4 v4 = *(const short4*)((const short*)V + rowbase + (size_t)t * DIM + d4 * 4);
    const short* kk = (const short*)&k4;
    const short* vv = (const short*)&v4;
#pragma unroll
    for (int j = 0; j < 4; ++j) {
      int e = d4 * 4 + j;
      int sl = ((t >> 3) ^ (e & 7)) * 16 + (t & 7) * 2;
      *(short*)((char*)Kt + e * 128 + sl) = kk[j];
      *(short*)((char*)Vt + e * 128 + sl) = vv[j];
    }
  }
  __syncthreads();

  if (tid < Dd) {
    float s = 0.f;
    for (int t = 0; t < CH; ++t) {
      unsigned short u = *(const unsigned short*)(
          (char*)Kt + tid * 128 + (((t >> 3) ^ (tid & 7)) * 16) + (t & 7) * 2);
      s += bf2f(u);
    }
    zc[((size_t)(b * Hh + h) * NC + c) * Dd + tid] = s;
  }

  f32x4 a[4];
#pragma unroll
  for (int nf = 0; nf < 4; ++nf) a[nf] = (f32x4){0.f, 0.f, 0.f, 0.f};
  const int rd = w * 16 + lr;
#pragma unroll
  for (int ks = 0; ks < 2; ++ks) {
    bf16x8 af = *(const bf16x8*)((char*)Kt + rd * 128 +
                                 (((ks * 4 + lg) ^ (rd & 7)) * 16));
#pragma unroll
    for (int nf = 0; nf < 4; ++nf) {
      int re = nf * 16 + lr;
      bf16x8 bf = *(const bf16x8*)((char*)Vt + re * 128 +
                                   (((ks * 4 + lg) ^ (re & 7)) * 16));
      a[nf] = __builtin_amdgcn_mfma_f32_16x16x32_bf16(af, bf, a[nf], 0, 0, 0);
    }
  }
  __syncthreads();

  // repack bf16 through LDS (8KB), coalesced 16B stores
  unsigned short* Cb = (unsigned short*)smem;  // [64][64] bf16
#pragma unroll
  for (int nf = 0; nf < 4; ++nf)
#pragma unroll
    for (int r = 0; r < 4; ++r)
      Cb[(w * 16 + lg * 4 + r) * 64 + nf * 16 + lr] = f2bf(a[nf][r]);
  __syncthreads();
  const size_t base = ((size_t)(b * Hh + h) * NC + c) * (Dd * Dd);
  const uint4* Cv = (const uint4*)Cb;
#pragma unroll
  for (int it = 0; it < 2; ++it) {
    int idx = tid + it * 256;   // 512 uint4 = 4096 bf16
    *(uint4*)&Sc[base + (size_t)idx * 8] = Cv[idx];
  }
}

// ---------------------------------------------------------------------------
// K3: exclusive prefix scan over chunks (bf16 Sc, fp32 accumulate).
// ---------------------------------------------------------------------------
__global__ __launch_bounds__(256) void k_scan(unsigned short* __restrict__ Sc,
                                              float* __restrict__ zc) {
  const int bh = blockIdx.x;
  const int o = blockIdx.y * 256 + threadIdx.x;
  const size_t base = (size_t)bh * NC * (Dd * Dd) + o;
  float run = 0.f;
#pragma unroll
  for (int c = 0; c < NC; ++c) {
    size_t off = base + (size_t)c * (Dd * Dd);
    float cur = bf2f(Sc[off]);
    Sc[off] = f2bf(run);
    run += cur;
  }
  if (blockIdx.y == 0 && threadIdx.x < Dd) {
    float rz = 0.f;
    for (int c = 0; c < NC; ++c) {
      size_t oz = ((size_t)bh * NC + c) * Dd + threadIdx.x;
      float cur = zc[oz];
      zc[oz] = rz;
      rz += cur;
    }
  }
}

// ---------------------------------------------------------------------------
// K4 (MFMA): per-chunk output (bf16 Sc; round-14).
// ---------------------------------------------------------------------------
__global__ __launch_bounds__(256) void k_out(
    const unsigned short* __restrict__ Q, const unsigned short* __restrict__ K,
    const unsigned short* __restrict__ V, const unsigned short* __restrict__ Sc,
    const float* __restrict__ zc, unsigned short* __restrict__ O) {
  __shared__ __align__(16) char smem[41216];
  short* Qs = (short*)smem;            // [64 t][64 d] swz
  short* Ks = (short*)(smem + 8192);   // [64 s][64 d] swz
  short* Vt = (short*)(smem + 16384);  // [64 e][64 s] swz
  short* St = (short*)(smem + 24576);  // [64 e][64 d] swz
  short* Ps = (short*)(smem + 32768);  // [64 t][64 s] swz; later out staging
  float* zs = (float*)(smem + 40960);
  const int c = blockIdx.x, h = blockIdx.y, b = blockIdx.z;
  const int tid = threadIdx.x;
  const int w = tid >> 6, l = tid & 63;
  const int lr = l & 15, lg = l >> 4;
  const size_t rowbase = ((size_t)(b * Tt + c * CH)) * DIM + h * Dd;

  {
    const int c16 = (l & 7) ^ ((l >> 3) & 7);
#pragma unroll
    for (int i = 0; i < 2; ++i) {
      int row = i * 32 + w * 8 + (l >> 3);
      gload16((const short*)Q + rowbase + (size_t)row * DIM + c16 * 8,
              (char*)Qs + (i * 32 + w * 8) * 128);
      gload16((const short*)K + rowbase + (size_t)row * DIM + c16 * 8,
              (char*)Ks + (i * 32 + w * 8) * 128);
    }
  }
  const size_t sbase = ((size_t)(b * Hh + h) * NC + c) * (Dd * Dd);
  if (tid < Dd) zs[tid] = zc[((size_t)(b * Hh + h) * NC + c) * Dd + tid];
#pragma unroll
  for (int it = 0; it < 4; ++it) {
    int idx = tid + it * 256;
    int t = idx >> 4, d4 = idx & 15;
    short4 v4 = *(const short4*)((const short*)V + rowbase + (size_t)t * DIM + d4 * 4);
    const short* vv = (const short*)&v4;
#pragma unroll
    for (int j = 0; j < 4; ++j) {
      int e = d4 * 4 + j;
      *(short*)((char*)Vt + e * 128 + (((t >> 3) ^ (e & 7)) * 16) + (t & 7) * 2) = vv[j];
    }
    short4 s4 = *(const short4*)((const short*)Sc + sbase + (size_t)t * 64 + d4 * 4);
    const short* sv = (const short*)&s4;
#pragma unroll
    for (int j = 0; j < 4; ++j) {
      int e = d4 * 4 + j;  // t here is the d index of S
      *(short*)((char*)St + e * 128 + (((t >> 3) ^ (e & 7)) * 16) + (t & 7) * 2) =
          sv[j];
    }
  }
  __syncthreads();

  f32x4 a0[4];
#pragma unroll
  for (int nf = 0; nf < 4; ++nf) a0[nf] = (f32x4){0.f, 0.f, 0.f, 0.f};
  const int rq = w * 16 + lr;
#pragma unroll
  for (int ks = 0; ks < 2; ++ks) {
    bf16x8 af = *(const bf16x8*)((char*)Qs + rq * 128 +
                                 (((ks * 4 + lg) ^ (rq & 7)) * 16));
#pragma unroll
    for (int nf = 0; nf < 4; ++nf) {
      int rk = nf * 16 + lr;
      bf16x8 bf = *(const bf16x8*)((char*)Ks + rk * 128 +
                                   (((ks * 4 + lg) ^ (rk & 7)) * 16));
      a0[nf] = __builtin_amdgcn_mfma_f32_16x16x32_bf16(af, bf, a0[nf], 0, 0, 0);
    }
  }

  float part[4] = {0.f, 0.f, 0.f, 0.f};
#pragma unroll
  for (int nf = 0; nf < 4; ++nf) {
    int col = nf * 16 + lr;
#pragma unroll
    for (int r = 0; r < 4; ++r) {
      int row = w * 16 + lg * 4 + r;
      float av = (col <= row) ? a0[nf][r] : 0.f;
      part[r] += av;
      *(short*)((char*)Ps + row * 128 +
                ((((nf * 2) + (lr >> 3)) ^ (row & 7)) * 16) + (lr & 7) * 2) =
          (short)f2bf(av);
    }
  }
#pragma unroll
  for (int r = 0; r < 4; ++r) {
    int row = w * 16 + lg * 4 + r;
#pragma unroll
    for (int j = 0; j < 4; ++j) {
      int d = lr + j * 16;
      unsigned short qu = *(const unsigned short*)(
          (char*)Qs + row * 128 + (((d >> 3) ^ (row & 7)) * 16) + (d & 7) * 2);
      part[r] += bf2f(qu) * zs[d];
    }
  }
  float inv[4];
#pragma unroll
  for (int r = 0; r < 4; ++r) {
    float s = part[r];
    s += __shfl_xor(s, 1);
    s += __shfl_xor(s, 2);
    s += __shfl_xor(s, 4);
    s += __shfl_xor(s, 8);
    inv[r] = 1.f / fmaxf(s, 1e-6f);
  }
  __syncthreads();

  f32x4 a1[4];
#pragma unroll
  for (int nf = 0; nf < 4; ++nf) a1[nf] = (f32x4){0.f, 0.f, 0.f, 0.f};
#pragma unroll
  for (int ks = 0; ks < 4; ++ks) {
    const char* abase = (ks < 2) ? (const char*)Ps : (const char*)Qs;
    const char* bbase = (ks < 2) ? (const char*)Vt : (const char*)St;
    int kslot = (ks & 1) * 4 + lg;
    bf16x8 af = *(const bf16x8*)(abase + rq * 128 + ((kslot ^ (rq & 7)) * 16));
#pragma unroll
    for (int nf = 0; nf < 4; ++nf) {
      int re = nf * 16 + lr;
      bf16x8 bf = *(const bf16x8*)(bbase + re * 128 + ((kslot ^ (re & 7)) * 16));
      a1[nf] = __builtin_amdgcn_mfma_f32_16x16x32_bf16(af, bf, a1[nf], 0, 0, 0);
    }
  }
  __syncthreads();

#pragma unroll
  for (int nf = 0; nf < 4; ++nf)
#pragma unroll
    for (int r = 0; r < 4; ++r) {
      int row = w * 16 + lg * 4 + r;
      Ps[row * 64 + nf * 16 + lr] = (short)f2bf(a1[nf][r] * inv[r]);
    }
  __syncthreads();
  const uint4* Pv = (const uint4*)Ps;
#pragma unroll
  for (int i = 0; i < 2; ++i) {
    int idx = tid + i * 256;
    int row = idx >> 3, uc = idx & 7;
    *(uint4*)((unsigned short*)O + rowbase + (size_t)row * DIM + uc * 8) = Pv[idx];
  }
}

// ---------------------------------------------------------------------------
// GEMM2: out = (O @ Wo) * G.  M=8192, K=256, N=768.  3-ring + read-ahead;
// two-pass fp32 LDS-repack epilogue with gate multiply.
// ---------------------------------------------------------------------------
__global__ __launch_bounds__(256, 3) void k_gemm2(
    const unsigned short* __restrict__ Ob, const unsigned short* __restrict__ WoT,
    const unsigned short* __restrict__ G, float* __restrict__ out) {
  __shared__ __align__(16) char smem[49152];
  short* A0 = (short*)smem;
  short* A1 = (short*)(smem + 8192);
  short* A2 = (short*)(smem + 16384);
  short* B0 = (short*)(smem + 24576);
  short* B1 = (short*)(smem + 32768);
  short* B2 = (short*)(smem + 40960);
  const int tid = threadIdx.x;
  const int w = tid >> 6, l = tid & 63;
  const int lr = l & 15, lg = l >> 4;
  const int wr = w >> 1, wc = w & 1;
  int mt, nt;
  xcd_tile(blockIdx.x, mt, nt);
  const int m0 = mt * 128, n0 = nt * 128;

  Stage32 st;
  st.init((const short*)Ob + (size_t)m0 * DIM, DIM,
          (const short*)WoT + (size_t)n0 * DIM, DIM, w, l);

  f32x4 acc[4][4];
#pragma unroll
  for (int i = 0; i < 4; ++i)
#pragma unroll
    for (int j = 0; j < 4; ++j) acc[i][j] = (f32x4){0.f, 0.f, 0.f, 0.f};

  kloop3p<DIM / 32>(st, A0, A1, A2, B0, B1, B2, acc, wr, wc, lr, lg);

  // ---- epilogue: two-pass fp32 repack (64x128 = 32KB per pass) ----
  float* Cf = (float*)smem;
#pragma unroll
  for (int half = 0; half < 2; ++half) {
    __syncthreads();
    if (wr == half) {
#pragma unroll
      for (int mi = 0; mi < 4; ++mi)
#pragma unroll
        for (int ni = 0; ni < 4; ++ni)
#pragma unroll
          for (int r = 0; r < 4; ++r)
            Cf[(mi * 16 + lg * 4 + r) * 128 + wc * 64 + ni * 16 + lr] =
                acc[mi][ni][r];
    }
    __syncthreads();
    const float4* Cv = (const float4*)Cf;
#pragma unroll
    for (int i = 0; i < 8; ++i) {
      int idx = tid + i * 256;          // 2048 float4 = 64x128 fp32
      int urow = idx >> 5, uc = idx & 31;
      float4 cv = Cv[idx];
      size_t go = (size_t)(m0 + half * 64 + urow) * DM + n0 + uc * 4;
      short4 g4 = *(const short4*)(G + go);
      float4 ov;
      ov.x = cv.x * bf2f(g4.x);
      ov.y = cv.y * bf2f(g4.y);
      ov.z = cv.z * bf2f(g4.z);
      ov.w = cv.w * bf2f(g4.w);
      *(float4*)(out + go) = ov;
    }
  }
}

// ---------------------------------------------------------------------------
extern "C" void kernel_launch(void* const* d_in, const int* in_sizes, int n_in,
                              void* d_out, int out_size, void* d_ws,
                              size_t ws_size, hipStream_t stream) {
  const float* x  = (const float*)d_in[0];
  const float* Wq = (const float*)d_in[1];
  const float* Wk = (const float*)d_in[2];
  const float* Wv = (const float*)d_in[3];
  const float* Wo = (const float*)d_in[4];
  const float* Wg = (const float*)d_in[5];
  float* out = (float*)d_out;

  char* p = (char*)d_ws;
  size_t off = 0;
  auto alloc = [&](size_t bytes) {
    void* r = p + off;
    off = (off + bytes + 255) & ~(size_t)255;
    return r;
  };
  unsigned short* xb  = (unsigned short*)alloc((size_t)BT * DM * 2);
  unsigned short* WT  = (unsigned short*)alloc((size_t)NQKVG * DM * 2);
  unsigned short* WoT = (unsigned short*)alloc((size_t)DM * DIM * 2);
  unsigned short* Q   = (unsigned short*)alloc((size_t)BT * DIM * 2);
  unsigned short* Kf  = (unsigned short*)alloc((size_t)BT * DIM * 2);
  unsigned short* Vf  = (unsigned short*)alloc((size_t)BT * DIM * 2);
  unsigned short* G   = (unsigned short*)alloc((size_t)BT * DM * 2);
  unsigned short* Ob  = (unsigned short*)alloc((size_t)BT * DIM * 2);
  unsigned short* Sc  = (unsigned short*)alloc((size_t)Bb * Hh * NC * Dd * Dd * 2);
  float* zc = (float*)alloc((size_t)Bb * Hh * NC * Dd * 4);

  // 1. fused input cast + weight transposes
  k_prep<<<dim3(3072 + 1344), dim3(256), 0, stream>>>(x, Wq, Wk, Wv, Wg, Wo,
                                                      xb, WT, WoT);

  // 2. fused QKV + gate projection (MFMA), N=1536
  k_gemm1<<<dim3(MT * (NQKVG / 128)), dim3(256), 0, stream>>>(
      xb, WT, Q, Kf, Vf, G);

  // 3. chunked linear attention (MFMA middle kernels)
  k_chunksum<<<dim3(NC, Hh, Bb), dim3(256), 0, stream>>>(Kf, Vf, Sc, zc);
  k_scan<<<dim3(Bb * Hh, Dd * Dd / 256), dim3(256), 0, stream>>>(Sc, zc);
  k_out<<<dim3(NC, Hh, Bb), dim3(256), 0, stream>>>(Q, Kf, Vf, Sc, zc, Ob);

  // 4. output GEMM * gate (MFMA)
  k_gemm2<<<dim3(MT * (DM / 128)), dim3(256), 0, stream>>>(Ob, WoT, G, out);
}